// Round 5
// baseline (495.969 us; speedup 1.0000x reference)
//
#include <hip/hip_runtime.h>

// Problem constants (B=2, S=1024, D=1024, F=4096, E=8)
#define T_TOK 2048
#define DD 1024
#define FF 4096
#define EE 8
#define MT 64           // expert m-tile. v2: 128 -> 64 (double grid: occupancy
                        // was the binding constraint, 24% w/ 2.5 blocks/CU)
#define MAX_SLOTS 40    // worst case sum_e ceil(cnt_e/64) <= 2048/64 + 7 = 39

typedef __attribute__((ext_vector_type(8))) short short8;
typedef __attribute__((ext_vector_type(4))) short short4v;
typedef __attribute__((ext_vector_type(4))) float floatx4;
typedef unsigned int u32;
typedef unsigned short u16;

// fp32 -> bf16 round-to-nearest-even, raw u16
static __device__ __forceinline__ u32 f2bf_u(float f){
  u32 u = __float_as_uint(f);
  u32 r = u + 0x7fffu + ((u >> 16) & 1u);
  return r >> 16;
}

static __device__ __forceinline__ short8 ldfrag(const u16* p){
  short4v lo = *(const short4v*)p;        // 2x 8B reads (72B row stride keeps 8B align)
  short4v hi = *(const short4v*)(p + 4);
  return __builtin_shufflevector(lo, hi, 0, 1, 2, 3, 4, 5, 6, 7);
}

// async 16B global->LDS (global_load_lds_dwordx4). LDS dest is wave-uniform;
// HW writes at ldsbase + lane*16. Global src address is per-lane (allows
// gather + pre-swizzled source, guide m173/m104 pattern).
static __device__ __forceinline__ void async_copy16(const void* g, void* l){
  __builtin_amdgcn_global_load_lds(
      (const __attribute__((address_space(1))) u32*)g,
      (__attribute__((address_space(3))) u32*)l, 16, 0, 0);
}

// ---------------------------------------------------------------------------
// FALLBACK router layer 1 (used only when workspace too small for split-K):
// H = relu(X @ W1 + b1), fp32. 64x64 tile, BK=16, 4x4 microtile. Also zeroes
// expert counters.
// ---------------------------------------------------------------------------
__global__ __launch_bounds__(256) void router_gemm1(
    const float* __restrict__ X, const float* __restrict__ W,
    const float* __restrict__ bias, float* __restrict__ H, int* counts)
{
  if (blockIdx.x == 0 && blockIdx.y == 0 && threadIdx.x < EE) counts[threadIdx.x] = 0;
  __shared__ float As[2][16][68];   // [k][m]
  __shared__ float Bs[2][16][68];   // [k][n]
  const int tid = threadIdx.x;
  const int tx = tid & 15, ty = tid >> 4;
  const int bm = blockIdx.y * 64, bn = blockIdx.x * 64;
  const int ar = tid >> 2, ak = (tid & 3) * 4;
  const int bk = tid >> 4, bn0 = (tid & 15) * 4;
  const float* aP = X + (size_t)(bm + ar) * DD;
  float acc[4][4] = {};
  float4 pa, pb;

  pa = *(const float4*)(aP + ak);
  pb = *(const float4*)(W + (size_t)bk * DD + bn + bn0);
  As[0][ak+0][ar] = pa.x; As[0][ak+1][ar] = pa.y;
  As[0][ak+2][ar] = pa.z; As[0][ak+3][ar] = pa.w;
  *(float4*)&Bs[0][bk][bn0] = pb;
  __syncthreads();

  for (int it = 0; it < DD/16; ++it){
    if (it + 1 < DD/16){
      const int kt = (it + 1) * 16;
      pa = *(const float4*)(aP + kt + ak);
      pb = *(const float4*)(W + (size_t)(kt + bk) * DD + bn + bn0);
    }
    const int buf = it & 1;
    #pragma unroll
    for (int k = 0; k < 16; ++k){
      float4 av = *(const float4*)&As[buf][k][ty*4];
      float4 bv = *(const float4*)&Bs[buf][k][tx*4];
      float am[4] = {av.x, av.y, av.z, av.w};
      float bm4[4] = {bv.x, bv.y, bv.z, bv.w};
      #pragma unroll
      for (int i = 0; i < 4; ++i)
        #pragma unroll
        for (int j = 0; j < 4; ++j)
          acc[i][j] += am[i] * bm4[j];
    }
    if (it + 1 < DD/16){
      const int nb2 = (it + 1) & 1;
      As[nb2][ak+0][ar] = pa.x; As[nb2][ak+1][ar] = pa.y;
      As[nb2][ak+2][ar] = pa.z; As[nb2][ak+3][ar] = pa.w;
      *(float4*)&Bs[nb2][bk][bn0] = pb;
      __syncthreads();
    }
  }
  #pragma unroll
  for (int i = 0; i < 4; ++i){
    float4 v;
    v.x = fmaxf(acc[i][0] + bias[bn + tx*4 + 0], 0.f);
    v.y = fmaxf(acc[i][1] + bias[bn + tx*4 + 1], 0.f);
    v.z = fmaxf(acc[i][2] + bias[bn + tx*4 + 2], 0.f);
    v.w = fmaxf(acc[i][3] + bias[bn + tx*4 + 3], 0.f);
    *(float4*)(H + (size_t)(bm + ty*4 + i) * DD + bn + tx*4) = v;
  }
}

// ---------------------------------------------------------------------------
// FAST router layer 1 v3: split-K=4 partial GEMM, fp32, no bias/relu (folded
// into logits kernel). 64x128 tile, 4x8 microtile, launch_bounds(256,4),
// grid 8 x 32 x 4 = 1024 blocks = 16 waves/CU. Verified in r4: dropped out
// of the top-5 (was 98us at VGPR=188 / 10.5% occ in v1). DO NOT revert to
// the 8x8 microtile. Partials: Hp[kc][t][d]. Zeroes counters.
// ---------------------------------------------------------------------------
__global__ __launch_bounds__(256, 4) void router_gemm1_v3(
    const float* __restrict__ X, const float* __restrict__ W,
    float* __restrict__ Hp, int* counts)
{
  if (blockIdx.x == 0 && blockIdx.y == 0 && blockIdx.z == 0 && threadIdx.x < EE)
    counts[threadIdx.x] = 0;
  __shared__ float As[2][16][68];    // [k][m: 64 + pad]
  __shared__ float Bs[2][16][132];   // [k][n: 128 + pad]
  const int tid = threadIdx.x;
  const int tx = tid & 15, ty = tid >> 4;
  const int bm = blockIdx.y * 64, bn = blockIdx.x * 128;
  const int kbase = blockIdx.z * (DD/4);
  const int ar = tid >> 2, ak = (tid & 3) * 4;   // A: 64 rows, 4 thr/row, 4 k each
  const int bk = tid >> 4, bn0 = (tid & 15) * 8; // B: 16 k-rows, 8 n each
  float acc[4][8] = {};
  float4 pa, pb0, pb1;

  auto issue = [&](int kt){
    pa  = *(const float4*)(X + (size_t)(bm + ar) * DD + kbase + kt + ak);
    const float* wp = W + (size_t)(kbase + kt + bk) * DD + bn + bn0;
    pb0 = *(const float4*)wp;
    pb1 = *(const float4*)(wp + 4);
  };
  auto stage = [&](int buf){
    As[buf][ak+0][ar] = pa.x; As[buf][ak+1][ar] = pa.y;
    As[buf][ak+2][ar] = pa.z; As[buf][ak+3][ar] = pa.w;
    *(float4*)&Bs[buf][bk][bn0]     = pb0;
    *(float4*)&Bs[buf][bk][bn0 + 4] = pb1;
  };

  issue(0); stage(0); __syncthreads();
  const int NIT = (DD/4)/16;    // 16
  for (int it = 0; it < NIT; ++it){
    if (it + 1 < NIT) issue((it + 1) * 16);
    const int buf = it & 1;
    #pragma unroll
    for (int k = 0; k < 16; ++k){
      float4 av  = *(const float4*)&As[buf][k][ty*4];
      float4 bv0 = *(const float4*)&Bs[buf][k][tx*8];
      float4 bv1 = *(const float4*)&Bs[buf][k][tx*8 + 4];
      float a[4] = {av.x, av.y, av.z, av.w};
      float b[8] = {bv0.x, bv0.y, bv0.z, bv0.w, bv1.x, bv1.y, bv1.z, bv1.w};
      #pragma unroll
      for (int i = 0; i < 4; ++i)
        #pragma unroll
        for (int j = 0; j < 8; ++j)
          acc[i][j] += a[i] * b[j];
    }
    if (it + 1 < NIT){ stage((it + 1) & 1); __syncthreads(); }
  }
  float* o = Hp + (size_t)blockIdx.z * T_TOK * DD;
  #pragma unroll
  for (int i = 0; i < 4; ++i){
    float4 v0 = {acc[i][0], acc[i][1], acc[i][2], acc[i][3]};
    float4 v1 = {acc[i][4], acc[i][5], acc[i][6], acc[i][7]};
    *(float4*)(o + (size_t)(bm + ty*4 + i) * DD + bn + tx*8)     = v0;
    *(float4*)(o + (size_t)(bm + ty*4 + i) * DD + bn + tx*8 + 4) = v1;
  }
}

// ---------------------------------------------------------------------------
// Router layer 2 + argmax (softmax monotone -> skip). One wave/token.
// SK path: h = relu(sum of 4 split-K partials + b1) on the fly (H never stored).
// ---------------------------------------------------------------------------
template<bool SK>
__global__ __launch_bounds__(64) void router_logits_argmax(
    const float* __restrict__ Hsrc, const float* __restrict__ b1,
    const float* __restrict__ W2, const float* __restrict__ b2,
    int* __restrict__ eidx, int* __restrict__ counts)
{
  const int t = blockIdx.x;
  const int lane = threadIdx.x;
  float acc[8] = {0,0,0,0,0,0,0,0};
  for (int d = lane; d < DD; d += 64){
    float hv;
    if constexpr (SK){
      const size_t TD = (size_t)T_TOK * DD;
      const float* p = Hsrc + (size_t)t * DD + d;
      hv = fmaxf(p[0] + p[TD] + p[2*TD] + p[3*TD] + b1[d], 0.f);
    } else {
      hv = Hsrc[(size_t)t * DD + d];
    }
    float4 w0 = *(const float4*)(W2 + (size_t)d * 8);
    float4 w1 = *(const float4*)(W2 + (size_t)d * 8 + 4);
    acc[0] += hv * w0.x; acc[1] += hv * w0.y; acc[2] += hv * w0.z; acc[3] += hv * w0.w;
    acc[4] += hv * w1.x; acc[5] += hv * w1.y; acc[6] += hv * w1.z; acc[7] += hv * w1.w;
  }
  #pragma unroll
  for (int s = 32; s > 0; s >>= 1)
    #pragma unroll
    for (int e2 = 0; e2 < 8; ++e2)
      acc[e2] += __shfl_down(acc[e2], s, 64);
  if (lane == 0){
    int best = 0; float bv = acc[0] + b2[0];
    #pragma unroll
    for (int e2 = 1; e2 < 8; ++e2){
      float v = acc[e2] + b2[e2];
      if (v > bv){ bv = v; best = e2; }
    }
    eidx[t] = best;
    atomicAdd(&counts[best], 1);
  }
}

// Prefix-scan + compact (expert, m0) slot table so expert GEMM grids launch
// only ~live m-blocks.
__global__ void scan_offsets(const int* __restrict__ counts, int* __restrict__ offsets,
                             int* __restrict__ cursors, int* __restrict__ slot_e,
                             int* __restrict__ slot_m0, int* __restrict__ nslots)
{
  if (threadIdx.x == 0 && blockIdx.x == 0){
    int s = 0, ns = 0;
    for (int e = 0; e < EE; ++e){
      offsets[e] = s; cursors[e] = s;
      for (int m0 = 0; m0 < counts[e]; m0 += MT){ slot_e[ns] = e; slot_m0[ns] = m0; ++ns; }
      s += counts[e];
    }
    offsets[EE] = s;
    *nslots = ns;
  }
}

__global__ __launch_bounds__(256) void scatter_tokens(
    const int* __restrict__ eidx, int* __restrict__ cursors, int* __restrict__ perm)
{
  int t = blockIdx.x * 256 + threadIdx.x;
  if (t < T_TOK){
    int e = eidx[t];
    int p = atomicAdd(&cursors[e], 1);
    perm[p] = t;
  }
}

// Gather+convert X rows into permuted order, bf16: Xp[p][:] = bf16(X[perm[p]][:]).
// Makes expert-GEMM-1's A operand a contiguous bf16 slab -> global_load_lds.
__global__ __launch_bounds__(256) void gather_convert_x(
    const float* __restrict__ X, const int* __restrict__ perm, u16* __restrict__ Xp)
{
  const int p = blockIdx.x;
  const int t = perm[p];
  const float4 v = *(const float4*)(X + (size_t)t * DD + threadIdx.x * 4);
  u32 w0 = f2bf_u(v.x) | (f2bf_u(v.y) << 16);
  u32 w1 = f2bf_u(v.z) | (f2bf_u(v.w) << 16);
  *(uint2*)(Xp + (size_t)p * DD + threadIdx.x * 4) = make_uint2(w0, w1);
}

// ---------------------------------------------------------------------------
// Expert FFN GEMMs, bf16 MFMA 16x16x32. v2 (this round): MT 128->64, grids
// doubled. r4 post-mortem: SECOND had 2.5 live blocks/CU -> 24% occupancy ->
// per-iter vmcnt(0) drain (~900cyc HBM latency) uncovered; MfmaUtil 8.5%.
// Occupancy, not BW, was binding (hbm 1.6 of 6.3 TB/s).
// FIRST : hid[off+m][:] = relu(Xp[off+m][:] @ w1[e] + b1[e])  K=1024 N=4096, tile 64x128
// !FIRST: part[kc]     = hid[off+m][:] @ w2[e]                K=4096 N=1024, tile 64x64, gk=2
// BK=32 double-buffered. A: global_load_lds (1 inst/wave) with XOR slot
// swizzle on the per-lane SOURCE (LDS linear, rule #21). B: reg-prefetch
// fp32 -> bf16 transpose to Bs[n][36 shorts] (72B rows, conflict-free).
// 4 waves split along n (wn = wv*NW/4); each wave 64m x NW/4 n.
// ---------------------------------------------------------------------------
template<bool FIRST>
__global__ __launch_bounds__(256) void expert_gemm(
    const u16*  __restrict__ Ap,      // FIRST: Xp [T][DD]; else hid [T][FF]
    const float* __restrict__ Wall,   // [E][K][N] fp32
    const float* __restrict__ Ball,   // [E][N]
    u16*  __restrict__ hidOut,        // FIRST output
    float* __restrict__ Yout,         // !FIRST direct output (gridK==1)
    float* __restrict__ Part,         // !FIRST split-K partials [gridK][T][DD]
    const int* __restrict__ perm,
    const int* __restrict__ offsets,
    const int* __restrict__ slot_e,
    const int* __restrict__ slot_m0,
    const int* __restrict__ nslots,
    const int gridK)
{
  constexpr int K  = FIRST ? DD : FF;
  constexpr int N  = FIRST ? FF : DD;
  constexpr int NW = FIRST ? 128 : 64;   // n-tile
  constexpr int NJ = NW / 64;            // per-wave 16-col frags (2 or 1)

  const int slot = blockIdx.y;
  if (slot >= *nslots) return;
  const int e   = slot_e[slot];
  const int m0  = slot_m0[slot];
  const int off = offsets[e];
  const int cnt = offsets[e+1] - off;
  const int nb  = blockIdx.x * NW;
  const int kc  = blockIdx.z;
  const int Kc  = FIRST ? K : (K / gridK);
  const int kb  = kc * Kc;
  const int NIT = Kc / 32;
  const float* W = Wall + (size_t)e * K * N;

  __shared__ u16 As[2][MT * 32];   // [m:64][32k] bf16, linear (gload_lds dest)
  __shared__ u16 Bs[2][NW * 36];   // [n][32k + 4 pad] bf16

  const int tid  = threadIdx.x;
  const int lane = tid & 63;
  const int wv   = tid >> 6;

  // --- A staging: ONE global_load_lds per wave; wave wv covers rows
  // [wv*16, wv*16+16). lane -> row wv*16 + (lane>>2), phys 16B slot lane&3;
  // fetch LOGICAL slot q = phys ^ ((row>>1)&3) so the read-side XOR is linear.
  const int ar = wv * 16 + (lane >> 2);
  const int aq = (lane & 3) ^ ((ar >> 1) & 3);
  int rowg = off + m0 + ar;
  if (rowg > T_TOK - 1) rowg = T_TOK - 1;   // tail clamp (stores guarded)
  const u16* asrc = Ap + (size_t)rowg * K + kb + aq * 8;
  auto stageA = [&](int buf, int it){
    async_copy16(asrc + it * 32, &As[buf][wv * 512]);
  };

  // --- B staging: thread -> k-dword dk2 (pair of k rows), 8 (FIRST) / 4 n cols.
  const int dk2 = tid >> 4;               // 0..15
  const int bn0 = (tid & 15) * (NW / 16); // *8 or *4
  float4 fb0, fb1, fb2, fb3;
  auto issueB = [&](int it){
    const float* r0 = W + (size_t)(kb + it * 32 + 2 * dk2) * N + nb + bn0;
    fb0 = *(const float4*)r0;
    fb2 = *(const float4*)(r0 + N);
    if constexpr (FIRST){
      fb1 = *(const float4*)(r0 + 4);
      fb3 = *(const float4*)(r0 + N + 4);
    }
  };
  auto stageB = [&](int buf){
    float l0[4] = {fb0.x, fb0.y, fb0.z, fb0.w};
    float h0[4] = {fb2.x, fb2.y, fb2.z, fb2.w};
    #pragma unroll
    for (int j = 0; j < 4; ++j)
      *(u32*)&Bs[buf][(bn0 + j) * 36 + 2 * dk2] = f2bf_u(l0[j]) | (f2bf_u(h0[j]) << 16);
    if constexpr (FIRST){
      float l1[4] = {fb1.x, fb1.y, fb1.z, fb1.w};
      float h1[4] = {fb3.x, fb3.y, fb3.z, fb3.w};
      #pragma unroll
      for (int j = 0; j < 4; ++j)
        *(u32*)&Bs[buf][(bn0 + 4 + j) * 36 + 2 * dk2] = f2bf_u(l1[j]) | (f2bf_u(h1[j]) << 16);
    }
  };

  // --- compute: all 4 waves share the 64 m rows; wave owns n strip wv*NW/4.
  const int wn   = wv * (NW / 4);
  const int lrow = lane & 15;
  const int lq   = lane >> 4;

  floatx4 acc[4][NJ];
  #pragma unroll
  for (int i = 0; i < 4; ++i)
    #pragma unroll
    for (int j = 0; j < NJ; ++j)
      acc[i][j] = (floatx4){0.f, 0.f, 0.f, 0.f};

  auto compute = [&](int buf){
    short8 af[4], bfr[NJ];
    #pragma unroll
    for (int i = 0; i < 4; ++i){
      const int r  = i * 16 + lrow;
      const int sl = lq ^ ((r >> 1) & 3);
      af[i] = *(const short8*)&As[buf][r * 32 + sl * 8];
    }
    #pragma unroll
    for (int j = 0; j < NJ; ++j){
      const int nn = wn + j * 16 + lrow;
      bfr[j] = ldfrag(&Bs[buf][nn * 36 + lq * 8]);
    }
    #pragma unroll
    for (int i = 0; i < 4; ++i)
      #pragma unroll
      for (int j = 0; j < NJ; ++j)
        acc[i][j] = __builtin_amdgcn_mfma_f32_16x16x32_bf16(af[i], bfr[j], acc[i][j], 0, 0, 0);
  };

  // pipeline: issue(k+1) / async A(k+1) -> compute(k) -> stage B(k+1) -> barrier
  issueB(0);
  stageA(0, 0);
  stageB(0);
  __syncthreads();
  for (int it = 0; it < NIT; ++it){
    const int buf = it & 1;
    if (it + 1 < NIT){
      issueB(it + 1);
      stageA(buf ^ 1, it + 1);
    }
    compute(buf);
    if (it + 1 < NIT){
      stageB(buf ^ 1);
      __syncthreads();
    }
  }

  // epilogue: C/D layout col=lane&15, row=lq*4+reg
  #pragma unroll
  for (int i = 0; i < 4; ++i){
    #pragma unroll
    for (int j = 0; j < NJ; ++j){
      const int n = nb + wn + j * 16 + lrow;
      const float bv = Ball[(size_t)e * N + n];
      #pragma unroll
      for (int r = 0; r < 4; ++r){
        const int m = m0 + i * 16 + lq * 4 + r;
        if (m < cnt){
          float v = acc[i][j][r];
          if constexpr (FIRST){
            v = fmaxf(v + bv, 0.f);
            hidOut[(size_t)(off + m) * FF + n] = (u16)f2bf_u(v);
          } else {
            if (gridK == 1){
              Yout[(size_t)perm[off + m] * DD + n] = v + bv;
            } else {
              Part[(size_t)kc * T_TOK * DD + (size_t)(off + m) * DD + n] = v;
            }
          }
        }
      }
    }
  }
}

// Sum split-K partials of expert GEMM 2, add bias, scatter to output rows.
__global__ __launch_bounds__(256) void reduce_second(
    const float* __restrict__ Part, const float* __restrict__ Ball,
    const int* __restrict__ perm, const int* __restrict__ eidx,
    float* __restrict__ out)
{
  const int p = blockIdx.x;
  const int t = perm[p];
  const int e = eidx[t];
  const int d = threadIdx.x * 4;
  const float4 v0 = *(const float4*)(Part + (size_t)p * DD + d);
  const float4 v1 = *(const float4*)(Part + (size_t)T_TOK * DD + (size_t)p * DD + d);
  const float4 bb = *(const float4*)(Ball + (size_t)e * DD + d);
  float4 o;
  o.x = v0.x + v1.x + bb.x;
  o.y = v0.y + v1.y + bb.y;
  o.z = v0.z + v1.z + bb.z;
  o.w = v0.w + v1.w + bb.w;
  *(float4*)(out + (size_t)t * DD + d) = o;
}

extern "C" void kernel_launch(void* const* d_in, const int* in_sizes, int n_in,
                              void* d_out, int out_size, void* d_ws, size_t ws_size,
                              hipStream_t stream)
{
  const float* X   = (const float*)d_in[0];
  const float* rw1 = (const float*)d_in[1];
  const float* rb1 = (const float*)d_in[2];
  const float* rw2 = (const float*)d_in[3];
  const float* rb2 = (const float*)d_in[4];
  const float* ew1 = (const float*)d_in[5];
  const float* eb1 = (const float*)d_in[6];
  const float* ew2 = (const float*)d_in[7];
  const float* eb2 = (const float*)d_in[8];
  float* out = (float*)d_out;

  const size_t MB = (size_t)1 << 20;
  // Fast layout: [0,32MB) router partials (later reused: [0,4MB) Xp, [4,20MB)
  // expert partials) | [32,48MB) hid bf16 | [48MB,..) ints.   (~48.02 MB)
  // Fallback layout (24.33 MB): [0,8MB) H (later Xp) | [8,24MB) hid | ints.
  const bool fast = ws_size >= 48 * MB + 65536;

  char* w = (char*)d_ws;
  float* rpart = nullptr; float* H = nullptr; float* epart = nullptr;
  u16* Xp; u16* hid; char* intbase;
  if (fast){
    rpart = (float*)w;
    Xp    = (u16*)w;                       // overlays rpart (dead after logits)
    epart = (float*)(w + 4 * MB);          // 16 MB, used only in expert GEMM 2
    hid   = (u16*)(w + 32 * MB);
    intbase = w + 48 * MB;
  } else {
    H   = (float*)w;
    Xp  = (u16*)w;                         // overlays H (dead after logits)
    hid = (u16*)(w + 8 * MB);
    intbase = w + 24 * MB;
  }
  int* ip      = (int*)intbase;
  int* eidx    = ip;  ip += T_TOK;
  int* perm    = ip;  ip += T_TOK;
  int* counts  = ip;  ip += 16;
  int* offsets = ip;  ip += 16;
  int* cursors = ip;  ip += 16;
  int* slot_e  = ip;  ip += 64;
  int* slot_m0 = ip;  ip += 64;
  int* nslots  = ip;  ip += 4;

  if (fast){
    router_gemm1_v3<<<dim3(DD/128, T_TOK/64, 4), 256, 0, stream>>>(X, rw1, rpart, counts);
    router_logits_argmax<true><<<dim3(T_TOK), 64, 0, stream>>>(rpart, rb1, rw2, rb2, eidx, counts);
  } else {
    router_gemm1<<<dim3(DD/64, T_TOK/64), 256, 0, stream>>>(X, rw1, rb1, H, counts);
    router_logits_argmax<false><<<dim3(T_TOK), 64, 0, stream>>>(H, rb1, rw2, rb2, eidx, counts);
  }
  scan_offsets<<<dim3(1), 64, 0, stream>>>(counts, offsets, cursors, slot_e, slot_m0, nslots);
  scatter_tokens<<<dim3(T_TOK/256), 256, 0, stream>>>(eidx, cursors, perm);
  gather_convert_x<<<dim3(T_TOK), 256, 0, stream>>>(X, perm, Xp);

  expert_gemm<true><<<dim3(FF/128, MAX_SLOTS, 1), 256, 0, stream>>>(
      Xp, ew1, eb1, hid, nullptr, nullptr, perm, offsets, slot_e, slot_m0, nslots, 1);

  const int gk = fast ? 2 : 1;
  expert_gemm<false><<<dim3(DD/64, MAX_SLOTS, gk), 256, 0, stream>>>(
      hid, ew2, eb2, nullptr, out, epart, perm, offsets, slot_e, slot_m0, nslots, gk);
  if (fast)
    reduce_second<<<dim3(T_TOK), 256, 0, stream>>>(epart, eb2, perm, eidx, out);
}

// Round 6
// 480.053 us; speedup vs baseline: 1.0332x; 1.0332x over previous
//
#include <hip/hip_runtime.h>

// Problem constants (B=2, S=1024, D=1024, F=4096, E=8)
#define T_TOK 2048
#define DD 1024
#define FF 4096
#define EE 8
#define MT 128          // expert m-tile. r5 lesson: MT=64 doubled occupancy
                        // (24->44%) but dur flat & traffic doubled -> occupancy
                        // is NOT the lever; per-CU resident per-iter FLOPs
                        // (blocks/CU x MT*NW*BK) is. 128x128 maximizes it.
#define MAX_SLOTS 24    // sum_e ceil(cnt_e/128) <= 16 + 7 < 24

typedef __attribute__((ext_vector_type(8))) short short8;
typedef __attribute__((ext_vector_type(4))) short short4v;
typedef __attribute__((ext_vector_type(4))) float floatx4;
typedef unsigned int u32;
typedef unsigned short u16;

// fp32 -> bf16 round-to-nearest-even, raw u16
static __device__ __forceinline__ u32 f2bf_u(float f){
  u32 u = __float_as_uint(f);
  u32 r = u + 0x7fffu + ((u >> 16) & 1u);
  return r >> 16;
}

static __device__ __forceinline__ short8 ldfrag(const u16* p){
  short4v lo = *(const short4v*)p;        // 2x 8B reads (72B row stride keeps 8B align)
  short4v hi = *(const short4v*)(p + 4);
  return __builtin_shufflevector(lo, hi, 0, 1, 2, 3, 4, 5, 6, 7);
}

// async 16B global->LDS (global_load_lds_dwordx4). LDS dest is wave-uniform;
// HW writes at ldsbase + lane*16. Global src address is per-lane (allows
// gather + pre-swizzled source, guide m173/m104 pattern).
static __device__ __forceinline__ void async_copy16(const void* g, void* l){
  __builtin_amdgcn_global_load_lds(
      (const __attribute__((address_space(1))) u32*)g,
      (__attribute__((address_space(3))) u32*)l, 16, 0, 0);
}

// ---------------------------------------------------------------------------
// FALLBACK router layer 1 (used only when workspace too small for split-K):
// H = relu(X @ W1 + b1), fp32. 64x64 tile, BK=16, 4x4 microtile. Also zeroes
// expert counters.
// ---------------------------------------------------------------------------
__global__ __launch_bounds__(256) void router_gemm1(
    const float* __restrict__ X, const float* __restrict__ W,
    const float* __restrict__ bias, float* __restrict__ H, int* counts)
{
  if (blockIdx.x == 0 && blockIdx.y == 0 && threadIdx.x < EE) counts[threadIdx.x] = 0;
  __shared__ float As[2][16][68];   // [k][m]
  __shared__ float Bs[2][16][68];   // [k][n]
  const int tid = threadIdx.x;
  const int tx = tid & 15, ty = tid >> 4;
  const int bm = blockIdx.y * 64, bn = blockIdx.x * 64;
  const int ar = tid >> 2, ak = (tid & 3) * 4;
  const int bk = tid >> 4, bn0 = (tid & 15) * 4;
  const float* aP = X + (size_t)(bm + ar) * DD;
  float acc[4][4] = {};
  float4 pa, pb;

  pa = *(const float4*)(aP + ak);
  pb = *(const float4*)(W + (size_t)bk * DD + bn + bn0);
  As[0][ak+0][ar] = pa.x; As[0][ak+1][ar] = pa.y;
  As[0][ak+2][ar] = pa.z; As[0][ak+3][ar] = pa.w;
  *(float4*)&Bs[0][bk][bn0] = pb;
  __syncthreads();

  for (int it = 0; it < DD/16; ++it){
    if (it + 1 < DD/16){
      const int kt = (it + 1) * 16;
      pa = *(const float4*)(aP + kt + ak);
      pb = *(const float4*)(W + (size_t)(kt + bk) * DD + bn + bn0);
    }
    const int buf = it & 1;
    #pragma unroll
    for (int k = 0; k < 16; ++k){
      float4 av = *(const float4*)&As[buf][k][ty*4];
      float4 bv = *(const float4*)&Bs[buf][k][tx*4];
      float am[4] = {av.x, av.y, av.z, av.w};
      float bm4[4] = {bv.x, bv.y, bv.z, bv.w};
      #pragma unroll
      for (int i = 0; i < 4; ++i)
        #pragma unroll
        for (int j = 0; j < 4; ++j)
          acc[i][j] += am[i] * bm4[j];
    }
    if (it + 1 < DD/16){
      const int nb2 = (it + 1) & 1;
      As[nb2][ak+0][ar] = pa.x; As[nb2][ak+1][ar] = pa.y;
      As[nb2][ak+2][ar] = pa.z; As[nb2][ak+3][ar] = pa.w;
      *(float4*)&Bs[nb2][bk][bn0] = pb;
      __syncthreads();
    }
  }
  #pragma unroll
  for (int i = 0; i < 4; ++i){
    float4 v;
    v.x = fmaxf(acc[i][0] + bias[bn + tx*4 + 0], 0.f);
    v.y = fmaxf(acc[i][1] + bias[bn + tx*4 + 1], 0.f);
    v.z = fmaxf(acc[i][2] + bias[bn + tx*4 + 2], 0.f);
    v.w = fmaxf(acc[i][3] + bias[bn + tx*4 + 3], 0.f);
    *(float4*)(H + (size_t)(bm + ty*4 + i) * DD + bn + tx*4) = v;
  }
}

// ---------------------------------------------------------------------------
// FAST router layer 1 v3: split-K=4 partial GEMM, fp32, no bias/relu (folded
// into logits kernel). 64x128 tile, 4x8 microtile, launch_bounds(256,4),
// grid 8 x 32 x 4 = 1024 blocks = 16 waves/CU. Verified in r4: dropped out
// of the top-5 (was 98us at VGPR=188 / 10.5% occ in v1). DO NOT revert to
// the 8x8 microtile. Partials: Hp[kc][t][d]. Zeroes counters.
// ---------------------------------------------------------------------------
__global__ __launch_bounds__(256, 4) void router_gemm1_v3(
    const float* __restrict__ X, const float* __restrict__ W,
    float* __restrict__ Hp, int* counts)
{
  if (blockIdx.x == 0 && blockIdx.y == 0 && blockIdx.z == 0 && threadIdx.x < EE)
    counts[threadIdx.x] = 0;
  __shared__ float As[2][16][68];    // [k][m: 64 + pad]
  __shared__ float Bs[2][16][132];   // [k][n: 128 + pad]
  const int tid = threadIdx.x;
  const int tx = tid & 15, ty = tid >> 4;
  const int bm = blockIdx.y * 64, bn = blockIdx.x * 128;
  const int kbase = blockIdx.z * (DD/4);
  const int ar = tid >> 2, ak = (tid & 3) * 4;   // A: 64 rows, 4 thr/row, 4 k each
  const int bk = tid >> 4, bn0 = (tid & 15) * 8; // B: 16 k-rows, 8 n each
  float acc[4][8] = {};
  float4 pa, pb0, pb1;

  auto issue = [&](int kt){
    pa  = *(const float4*)(X + (size_t)(bm + ar) * DD + kbase + kt + ak);
    const float* wp = W + (size_t)(kbase + kt + bk) * DD + bn + bn0;
    pb0 = *(const float4*)wp;
    pb1 = *(const float4*)(wp + 4);
  };
  auto stage = [&](int buf){
    As[buf][ak+0][ar] = pa.x; As[buf][ak+1][ar] = pa.y;
    As[buf][ak+2][ar] = pa.z; As[buf][ak+3][ar] = pa.w;
    *(float4*)&Bs[buf][bk][bn0]     = pb0;
    *(float4*)&Bs[buf][bk][bn0 + 4] = pb1;
  };

  issue(0); stage(0); __syncthreads();
  const int NIT = (DD/4)/16;    // 16
  for (int it = 0; it < NIT; ++it){
    if (it + 1 < NIT) issue((it + 1) * 16);
    const int buf = it & 1;
    #pragma unroll
    for (int k = 0; k < 16; ++k){
      float4 av  = *(const float4*)&As[buf][k][ty*4];
      float4 bv0 = *(const float4*)&Bs[buf][k][tx*8];
      float4 bv1 = *(const float4*)&Bs[buf][k][tx*8 + 4];
      float a[4] = {av.x, av.y, av.z, av.w};
      float b[8] = {bv0.x, bv0.y, bv0.z, bv0.w, bv1.x, bv1.y, bv1.z, bv1.w};
      #pragma unroll
      for (int i = 0; i < 4; ++i)
        #pragma unroll
        for (int j = 0; j < 8; ++j)
          acc[i][j] += a[i] * b[j];
    }
    if (it + 1 < NIT){ stage((it + 1) & 1); __syncthreads(); }
  }
  float* o = Hp + (size_t)blockIdx.z * T_TOK * DD;
  #pragma unroll
  for (int i = 0; i < 4; ++i){
    float4 v0 = {acc[i][0], acc[i][1], acc[i][2], acc[i][3]};
    float4 v1 = {acc[i][4], acc[i][5], acc[i][6], acc[i][7]};
    *(float4*)(o + (size_t)(bm + ty*4 + i) * DD + bn + tx*8)     = v0;
    *(float4*)(o + (size_t)(bm + ty*4 + i) * DD + bn + tx*8 + 4) = v1;
  }
}

// ---------------------------------------------------------------------------
// Router layer 2 + argmax (softmax monotone -> skip). One wave/token.
// SK path: h = relu(sum of 4 split-K partials + b1) on the fly (H never stored).
// ---------------------------------------------------------------------------
template<bool SK>
__global__ __launch_bounds__(64) void router_logits_argmax(
    const float* __restrict__ Hsrc, const float* __restrict__ b1,
    const float* __restrict__ W2, const float* __restrict__ b2,
    int* __restrict__ eidx, int* __restrict__ counts)
{
  const int t = blockIdx.x;
  const int lane = threadIdx.x;
  float acc[8] = {0,0,0,0,0,0,0,0};
  for (int d = lane; d < DD; d += 64){
    float hv;
    if constexpr (SK){
      const size_t TD = (size_t)T_TOK * DD;
      const float* p = Hsrc + (size_t)t * DD + d;
      hv = fmaxf(p[0] + p[TD] + p[2*TD] + p[3*TD] + b1[d], 0.f);
    } else {
      hv = Hsrc[(size_t)t * DD + d];
    }
    float4 w0 = *(const float4*)(W2 + (size_t)d * 8);
    float4 w1 = *(const float4*)(W2 + (size_t)d * 8 + 4);
    acc[0] += hv * w0.x; acc[1] += hv * w0.y; acc[2] += hv * w0.z; acc[3] += hv * w0.w;
    acc[4] += hv * w1.x; acc[5] += hv * w1.y; acc[6] += hv * w1.z; acc[7] += hv * w1.w;
  }
  #pragma unroll
  for (int s = 32; s > 0; s >>= 1)
    #pragma unroll
    for (int e2 = 0; e2 < 8; ++e2)
      acc[e2] += __shfl_down(acc[e2], s, 64);
  if (lane == 0){
    int best = 0; float bv = acc[0] + b2[0];
    #pragma unroll
    for (int e2 = 1; e2 < 8; ++e2){
      float v = acc[e2] + b2[e2];
      if (v > bv){ bv = v; best = e2; }
    }
    eidx[t] = best;
    atomicAdd(&counts[best], 1);
  }
}

// Prefix-scan + compact (expert, m0) slot table so expert GEMM grids launch
// only ~live m-blocks.
__global__ void scan_offsets(const int* __restrict__ counts, int* __restrict__ offsets,
                             int* __restrict__ cursors, int* __restrict__ slot_e,
                             int* __restrict__ slot_m0, int* __restrict__ nslots)
{
  if (threadIdx.x == 0 && blockIdx.x == 0){
    int s = 0, ns = 0;
    for (int e = 0; e < EE; ++e){
      offsets[e] = s; cursors[e] = s;
      for (int m0 = 0; m0 < counts[e]; m0 += MT){ slot_e[ns] = e; slot_m0[ns] = m0; ++ns; }
      s += counts[e];
    }
    offsets[EE] = s;
    *nslots = ns;
  }
}

__global__ __launch_bounds__(256) void scatter_tokens(
    const int* __restrict__ eidx, int* __restrict__ cursors, int* __restrict__ perm)
{
  int t = blockIdx.x * 256 + threadIdx.x;
  if (t < T_TOK){
    int e = eidx[t];
    int p = atomicAdd(&cursors[e], 1);
    perm[p] = t;
  }
}

// Gather+convert X rows into permuted order, bf16: Xp[p][:] = bf16(X[perm[p]][:]).
// Makes expert-GEMM-1's A operand a contiguous bf16 slab -> global_load_lds.
__global__ __launch_bounds__(256) void gather_convert_x(
    const float* __restrict__ X, const int* __restrict__ perm, u16* __restrict__ Xp)
{
  const int p = blockIdx.x;
  const int t = perm[p];
  const float4 v = *(const float4*)(X + (size_t)t * DD + threadIdx.x * 4);
  u32 w0 = f2bf_u(v.x) | (f2bf_u(v.y) << 16);
  u32 w1 = f2bf_u(v.z) | (f2bf_u(v.w) << 16);
  *(uint2*)(Xp + (size_t)p * DD + threadIdx.x * 4) = make_uint2(w0, w1);
}

// ---------------------------------------------------------------------------
// Expert FFN GEMMs, bf16 MFMA 16x16x32. v3 (this round): BOTH gemms 128x128
// tile, 2x2 wave quadrants (64x64/wave, 4x4 frags, 16 MFMA/wave/iter).
// r5 lesson: per-CU resident per-iter FLOPs (blocks/CU x MT*NW*BK) is the
// lever, not occupancy. 128^2 maximizes MT*NW/(MT+NW) and halves B-strip
// re-read amplification (17 slots vs 33).
// FIRST : hid = relu(Xp @ w1[e] + b1)   K=1024 N=4096, grid 32 x slots
// !FIRST: part[kc] = hid @ w2[e]        K=4096 N=1024, grid 8 x slots x gk=4
//         (split-K=4 manufactures blocks for the small N; partials 32MB at
//          workspace base overlaying dead router partials/Xp)
// BK=32 double-buffered. A: 2x global_load_lds/wave, XOR slot swizzle on the
// per-lane SOURCE (LDS linear, rule #21). B: reg-prefetch fp32 -> bf16
// transpose to Bs[n][36 shorts] (72B rows, conflict-free frag reads).
// ---------------------------------------------------------------------------
template<bool FIRST>
__global__ __launch_bounds__(256) void expert_gemm(
    const u16*  __restrict__ Ap,      // FIRST: Xp [T][DD]; else hid [T][FF]
    const float* __restrict__ Wall,   // [E][K][N] fp32
    const float* __restrict__ Ball,   // [E][N]
    u16*  __restrict__ hidOut,        // FIRST output
    float* __restrict__ Yout,         // !FIRST direct output (gridK==1)
    float* __restrict__ Part,         // !FIRST split-K partials [gridK][T][DD]
    const int* __restrict__ perm,
    const int* __restrict__ offsets,
    const int* __restrict__ slot_e,
    const int* __restrict__ slot_m0,
    const int* __restrict__ nslots,
    const int gridK)
{
  constexpr int K  = FIRST ? DD : FF;
  constexpr int N  = FIRST ? FF : DD;
  constexpr int NW = 128;                // n-tile (both)

  const int slot = blockIdx.y;
  if (slot >= *nslots) return;
  const int e   = slot_e[slot];
  const int m0  = slot_m0[slot];
  const int off = offsets[e];
  const int cnt = offsets[e+1] - off;
  const int nb  = blockIdx.x * NW;
  const int kc  = blockIdx.z;
  const int Kc  = FIRST ? K : (K / gridK);
  const int kb  = kc * Kc;
  const int NIT = Kc / 32;
  const float* W = Wall + (size_t)e * K * N;

  __shared__ u16 As[2][MT * 32];   // [m:128][32k] bf16, linear (gload_lds dest)
  __shared__ u16 Bs[2][NW * 36];   // [n:128][32k + 4 pad] bf16

  const int tid  = threadIdx.x;
  const int lane = tid & 63;
  const int wv   = tid >> 6;

  // --- A staging: wave-inst wi = wv*2+s covers rows [wi*16, wi*16+16).
  // lane -> row wi*16 + (lane>>2), physical 16B slot lane&3; fetch the LOGICAL
  // slot q = phys ^ ((row>>1)&3) so the read-side XOR sees linear data.
  const u16* asrc[2];
  #pragma unroll
  for (int s = 0; s < 2; ++s){
    const int wi = wv * 2 + s;
    const int r  = wi * 16 + (lane >> 2);
    const int q  = (lane & 3) ^ ((r >> 1) & 3);
    int rowg = off + m0 + r;
    if (rowg > T_TOK - 1) rowg = T_TOK - 1;   // tail clamp (stores guarded)
    asrc[s] = Ap + (size_t)rowg * K + kb + q * 8;
  }
  auto stageA = [&](int buf, int it){
    #pragma unroll
    for (int s = 0; s < 2; ++s)
      async_copy16(asrc[s] + it * 32, &As[buf][(wv * 2 + s) * 512]);
  };

  // --- B staging: thread -> k-dword dk2 (pair of k rows) x 8 n values.
  const int dk2 = tid >> 4;           // 0..15
  const int bn0 = (tid & 15) * 8;
  float4 fb0, fb1, fb2, fb3;
  auto issueB = [&](int it){
    const float* r0 = W + (size_t)(kb + it * 32 + 2 * dk2) * N + nb + bn0;
    fb0 = *(const float4*)r0;
    fb1 = *(const float4*)(r0 + 4);
    fb2 = *(const float4*)(r0 + N);
    fb3 = *(const float4*)(r0 + N + 4);
  };
  auto stageB = [&](int buf){
    float l0[4] = {fb0.x, fb0.y, fb0.z, fb0.w};
    float h0[4] = {fb2.x, fb2.y, fb2.z, fb2.w};
    float l1[4] = {fb1.x, fb1.y, fb1.z, fb1.w};
    float h1[4] = {fb3.x, fb3.y, fb3.z, fb3.w};
    #pragma unroll
    for (int j = 0; j < 4; ++j){
      *(u32*)&Bs[buf][(bn0 + j) * 36 + 2 * dk2]     = f2bf_u(l0[j]) | (f2bf_u(h0[j]) << 16);
      *(u32*)&Bs[buf][(bn0 + 4 + j) * 36 + 2 * dk2] = f2bf_u(l1[j]) | (f2bf_u(h1[j]) << 16);
    }
  };

  // --- compute: wave (wm, wn) quadrant; 4 m-frags x 4 n-frags, K=32/iter.
  const int wm   = (wv & 1) * 64;
  const int wn   = (wv >> 1) * 64;
  const int lrow = lane & 15;
  const int lq   = lane >> 4;

  floatx4 acc[4][4];
  #pragma unroll
  for (int i = 0; i < 4; ++i)
    #pragma unroll
    for (int j = 0; j < 4; ++j)
      acc[i][j] = (floatx4){0.f, 0.f, 0.f, 0.f};

  auto compute = [&](int buf){
    short8 af[4], bfr[4];
    #pragma unroll
    for (int i = 0; i < 4; ++i){
      const int r  = wm + i * 16 + lrow;
      const int sl = lq ^ ((r >> 1) & 3);
      af[i] = *(const short8*)&As[buf][r * 32 + sl * 8];
    }
    #pragma unroll
    for (int j = 0; j < 4; ++j){
      const int nn = wn + j * 16 + lrow;
      bfr[j] = ldfrag(&Bs[buf][nn * 36 + lq * 8]);
    }
    #pragma unroll
    for (int i = 0; i < 4; ++i)
      #pragma unroll
      for (int j = 0; j < 4; ++j)
        acc[i][j] = __builtin_amdgcn_mfma_f32_16x16x32_bf16(af[i], bfr[j], acc[i][j], 0, 0, 0);
  };

  // pipeline: issue(k+1) / async A(k+1) -> compute(k) -> stage B(k+1) -> barrier
  issueB(0);
  stageA(0, 0);
  stageB(0);
  __syncthreads();
  for (int it = 0; it < NIT; ++it){
    const int buf = it & 1;
    if (it + 1 < NIT){
      issueB(it + 1);
      stageA(buf ^ 1, it + 1);
    }
    compute(buf);
    if (it + 1 < NIT){
      stageB(buf ^ 1);
      __syncthreads();
    }
  }

  // epilogue: C/D layout col=lane&15, row=lq*4+reg
  #pragma unroll
  for (int i = 0; i < 4; ++i){
    #pragma unroll
    for (int j = 0; j < 4; ++j){
      const int n = nb + wn + j * 16 + lrow;
      const float bv = Ball[(size_t)e * N + n];
      #pragma unroll
      for (int r = 0; r < 4; ++r){
        const int m = m0 + wm + i * 16 + lq * 4 + r;
        if (m < cnt){
          float v = acc[i][j][r];
          if constexpr (FIRST){
            v = fmaxf(v + bv, 0.f);
            hidOut[(size_t)(off + m) * FF + n] = (u16)f2bf_u(v);
          } else {
            if (gridK == 1){
              Yout[(size_t)perm[off + m] * DD + n] = v + bv;
            } else {
              Part[(size_t)kc * T_TOK * DD + (size_t)(off + m) * DD + n] = v;
            }
          }
        }
      }
    }
  }
}

// Sum 4 split-K partials of expert GEMM 2, add bias, scatter to output rows.
__global__ __launch_bounds__(256) void reduce_second(
    const float* __restrict__ Part, const float* __restrict__ Ball,
    const int* __restrict__ perm, const int* __restrict__ eidx,
    float* __restrict__ out)
{
  const size_t TD = (size_t)T_TOK * DD;
  const int p = blockIdx.x;
  const int t = perm[p];
  const int e = eidx[t];
  const int d = threadIdx.x * 4;
  const float4 v0 = *(const float4*)(Part + (size_t)p * DD + d);
  const float4 v1 = *(const float4*)(Part + TD   + (size_t)p * DD + d);
  const float4 v2 = *(const float4*)(Part + 2*TD + (size_t)p * DD + d);
  const float4 v3 = *(const float4*)(Part + 3*TD + (size_t)p * DD + d);
  const float4 bb = *(const float4*)(Ball + (size_t)e * DD + d);
  float4 o;
  o.x = v0.x + v1.x + v2.x + v3.x + bb.x;
  o.y = v0.y + v1.y + v2.y + v3.y + bb.y;
  o.z = v0.z + v1.z + v2.z + v3.z + bb.z;
  o.w = v0.w + v1.w + v2.w + v3.w + bb.w;
  *(float4*)(out + (size_t)t * DD + d) = o;
}

extern "C" void kernel_launch(void* const* d_in, const int* in_sizes, int n_in,
                              void* d_out, int out_size, void* d_ws, size_t ws_size,
                              hipStream_t stream)
{
  const float* X   = (const float*)d_in[0];
  const float* rw1 = (const float*)d_in[1];
  const float* rb1 = (const float*)d_in[2];
  const float* rw2 = (const float*)d_in[3];
  const float* rb2 = (const float*)d_in[4];
  const float* ew1 = (const float*)d_in[5];
  const float* eb1 = (const float*)d_in[6];
  const float* ew2 = (const float*)d_in[7];
  const float* eb2 = (const float*)d_in[8];
  float* out = (float*)d_out;

  const size_t MB = (size_t)1 << 20;
  // Fast layout (48 MB + ints, unchanged threshold):
  //   [0,32MB): router partials rpart (dead after logits) -> then Xp [0,4MB)
  //             (dead after FIRST) -> then expert partials epart [0,32MB)
  //             (gk=4, written by SECOND which runs after FIRST completes)
  //   [32,48MB): hid bf16
  //   [48MB,..): ints
  // Fallback layout (24.33 MB): [0,8MB) H (later Xp) | [8,24MB) hid | ints.
  const bool fast = ws_size >= 48 * MB + 65536;

  char* w = (char*)d_ws;
  float* rpart = nullptr; float* H = nullptr; float* epart = nullptr;
  u16* Xp; u16* hid; char* intbase;
  if (fast){
    rpart = (float*)w;
    Xp    = (u16*)w;                       // overlays rpart (dead after logits)
    epart = (float*)w;                     // overlays rpart+Xp (both dead by SECOND)
    hid   = (u16*)(w + 32 * MB);
    intbase = w + 48 * MB;
  } else {
    H   = (float*)w;
    Xp  = (u16*)w;                         // overlays H (dead after logits)
    hid = (u16*)(w + 8 * MB);
    intbase = w + 24 * MB;
  }
  int* ip      = (int*)intbase;
  int* eidx    = ip;  ip += T_TOK;
  int* perm    = ip;  ip += T_TOK;
  int* counts  = ip;  ip += 16;
  int* offsets = ip;  ip += 16;
  int* cursors = ip;  ip += 16;
  int* slot_e  = ip;  ip += 64;
  int* slot_m0 = ip;  ip += 64;
  int* nslots  = ip;  ip += 4;

  if (fast){
    router_gemm1_v3<<<dim3(DD/128, T_TOK/64, 4), 256, 0, stream>>>(X, rw1, rpart, counts);
    router_logits_argmax<true><<<dim3(T_TOK), 64, 0, stream>>>(rpart, rb1, rw2, rb2, eidx, counts);
  } else {
    router_gemm1<<<dim3(DD/64, T_TOK/64), 256, 0, stream>>>(X, rw1, rb1, H, counts);
    router_logits_argmax<false><<<dim3(T_TOK), 64, 0, stream>>>(H, rb1, rw2, rb2, eidx, counts);
  }
  scan_offsets<<<dim3(1), 64, 0, stream>>>(counts, offsets, cursors, slot_e, slot_m0, nslots);
  scatter_tokens<<<dim3(T_TOK/256), 256, 0, stream>>>(eidx, cursors, perm);
  gather_convert_x<<<dim3(T_TOK), 256, 0, stream>>>(X, perm, Xp);

  expert_gemm<true><<<dim3(FF/128, MAX_SLOTS, 1), 256, 0, stream>>>(
      Xp, ew1, eb1, hid, nullptr, nullptr, perm, offsets, slot_e, slot_m0, nslots, 1);

  const int gk = fast ? 4 : 1;
  expert_gemm<false><<<dim3(DD/128, MAX_SLOTS, gk), 256, 0, stream>>>(
      hid, ew2, eb2, nullptr, out, epart, perm, offsets, slot_e, slot_m0, nslots, gk);
  if (fast)
    reduce_second<<<dim3(T_TOK), 256, 0, stream>>>(epart, eb2, perm, eidx, out);
}